// Round 4
// baseline (484.669 us; speedup 1.0000x reference)
//
#include <hip/hip_runtime.h>
#include <hip/hip_cooperative_groups.h>

namespace cg = cooperative_groups;

typedef __attribute__((ext_vector_type(8))) short bf16x8;
typedef __attribute__((ext_vector_type(4))) float f32x4;
typedef __attribute__((ext_vector_type(2))) float f32x2;

__device__ __forceinline__ unsigned short f2bf(float x) {
  union { float f; unsigned u; } v; v.f = x;
  return (unsigned short)((v.u + 0x7fffu + ((v.u >> 16) & 1u)) >> 16);
}

// ================= CSR build: ONE cooperative kernel, 4 phases =================
// Bucket = dst >> 8 (256 nodes/bucket). Record = (dst&255)<<17 | src (25 bits).
// bcnt/bfill: one counter per 64B line (stride-16 ints). grid = B blocks (391),
// 2 blocks/CU co-resident (39KB LDS) -> cooperative launch capacity OK.
__global__ __launch_bounds__(256) void csr_k(const int* __restrict__ src,
                                             const int* __restrict__ dst,
                                             int* __restrict__ batom,
                                             unsigned* __restrict__ ebuf,
                                             int* __restrict__ csr,
                                             int* __restrict__ row_start,
                                             float* __restrict__ dinv,
                                             int N, int E, int B) {
  cg::grid_group grid = cg::this_grid();
  __shared__ int hist[512];
  __shared__ int base[512];
  __shared__ int sd[256];
  __shared__ int ofs[256];
  __shared__ int sorted[8192];  // bucket mean 4092, sigma ~64
  __shared__ int s_bs, s_m;

  int t = threadIdx.x;
  int* bcnt = batom;
  int* bfill = batom + (size_t)(B + 1) * 16;

  // ---- phase 0: zero the bucket counters (replaces hipMemsetAsync) ----
  int tot = (B + 1) * 32;
  for (int i = blockIdx.x * 256 + t; i < tot; i += gridDim.x * 256) batom[i] = 0;
  grid.sync();

  // ---- phase 1: global bucket histogram ----
  for (int i = t; i < B; i += 256) hist[i] = 0;
  __syncthreads();
  for (int e = blockIdx.x * 256 + t; e < E; e += gridDim.x * 256)
    atomicAdd(&hist[dst[e] >> 8], 1);
  __syncthreads();
  for (int i = t; i < B; i += 256)
    if (hist[i]) atomicAdd(&bcnt[i * 16], hist[i]);
  grid.sync();

  // ---- phase 2: bin — local bucket scan + per-block LDS hist + one reservation ----
  {
    int i0 = 2 * t, i1 = 2 * t + 1;
    int v0 = (i0 < B) ? bcnt[i0 * 16] : 0;
    int v1 = (i1 < B) ? bcnt[i1 * 16] : 0;
    int ts = v0 + v1;
    sd[t] = ts; __syncthreads();
    for (int off = 1; off < 256; off <<= 1) {
      int x = (t >= off) ? sd[t - off] : 0;
      __syncthreads();
      sd[t] += x;
      __syncthreads();
    }
    int excl = sd[t] - ts;
    base[i0] = excl;
    base[i1] = excl + v0;
    __syncthreads();

    int chunk = (E + gridDim.x - 1) / gridDim.x;
    int e0 = blockIdx.x * chunk;
    int e1 = e0 + chunk; if (e1 > E) e1 = E;
    for (int i = t; i < B; i += 256) hist[i] = 0;
    __syncthreads();
    for (int e = e0 + t; e < e1; e += 256) atomicAdd(&hist[dst[e] >> 8], 1);
    __syncthreads();
    for (int i = t; i < B; i += 256) {
      int c = hist[i];
      hist[i] = base[i] + (c ? atomicAdd(&bfill[i * 16], c) : 0);
    }
    __syncthreads();
    for (int e = e0 + t; e < e1; e += 256) {
      int d = dst[e];
      int b = d >> 8;
      int pos = atomicAdd(&hist[b], 1);  // LDS atomic
      ebuf[pos] = ((unsigned)(d & 255) << 17) | (unsigned)src[e];
    }
  }
  grid.sync();

  // ---- phase 3: per-bucket LDS counting sort -> coalesced CSR + row_start + dinv ----
  {
    int b = blockIdx.x;  // grid sized exactly B
    int i0 = 2 * t, i1 = 2 * t + 1;
    int v0 = (i0 < B) ? bcnt[i0 * 16] : 0;
    int v1 = (i1 < B) ? bcnt[i1 * 16] : 0;
    int ts = v0 + v1;
    sd[t] = ts; __syncthreads();
    for (int off = 1; off < 256; off <<= 1) {
      int x = (t >= off) ? sd[t - off] : 0;
      __syncthreads();
      sd[t] += x;
      __syncthreads();
    }
    int excl = sd[t] - ts;
    if (i0 == b) { s_bs = excl; s_m = v0; }
    if (i1 == b) { s_bs = excl + v0; s_m = v1; }
    if (b == 0 && t == 0) row_start[N] = E;
    __syncthreads();
    int bs = s_bs, m = s_m;
    if (m > 8192) m = 8192;

    hist[t] = 0;  // reuse as per-node count
    __syncthreads();
    for (int i = t; i < m; i += 256) atomicAdd(&hist[ebuf[bs + i] >> 17], 1);
    __syncthreads();
    int deg = hist[t];
    sd[t] = deg; __syncthreads();
    for (int off = 1; off < 256; off <<= 1) {
      int x = (t >= off) ? sd[t - off] : 0;
      __syncthreads();
      sd[t] += x;
      __syncthreads();
    }
    int nexcl = sd[t] - deg;
    ofs[t] = nexcl;
    int node = (b << 8) + t;
    if (node < N) {
      row_start[node] = bs + nexcl;
      dinv[node] = rsqrtf((float)(deg + 1));
    }
    __syncthreads();
    for (int i = t; i < m; i += 256) {
      unsigned r = ebuf[bs + i];
      int d = r >> 17;
      int p = atomicAdd(&ofs[d], 1);
      if (p < 8192) sorted[p] = (int)(r & 0x1FFFFu);
    }
    __syncthreads();
    for (int i = t; i < m; i += 256) csr[bs + i] = sorted[i];
  }
}

// ---------------- GEMM: [M,128] @ [128,NCOL] via 16x16x32 bf16 MFMA ----------------
// SCALE: multiply each output row by rowscale[row] before bf16 pack (dinv folding).
template <int NCOL, bool INF32, bool OUTF32, bool SCALE>
__global__ __launch_bounds__(256) void gemm_k(const void* __restrict__ Ap,
                                              const float* __restrict__ W,
                                              const float* __restrict__ bias,
                                              const float* __restrict__ rowscale,
                                              void* __restrict__ Cp, int M) {
  __shared__ __align__(16) unsigned short Ws[NCOL * 136];  // [n][k], pad k to 136
  int tid = threadIdx.x;
  for (int e = tid; e < 128 * NCOL; e += 256) {
    int k = e / NCOL, n = e % NCOL;
    Ws[n * 136 + k] = f2bf(W[e]);
  }
  __syncthreads();

  int wave = tid >> 6, lane = tid & 63;
  int q = lane >> 4, r = lane & 15;
  const int NT = NCOL / 16;
  int ntile = M >> 4;
  for (int tile = blockIdx.x * 4 + wave; tile < ntile; tile += gridDim.x * 4) {
    int row = tile * 16 + r;
    bf16x8 a[4];
    if (INF32) {
      const float* A = (const float*)Ap + (size_t)row * 128 + q * 8;
#pragma unroll
      for (int kk = 0; kk < 4; kk++) {
        const float4* p = (const float4*)(A + kk * 32);
        float4 f0 = p[0], f1 = p[1];
        bf16x8 tt;
        tt[0] = (short)f2bf(f0.x); tt[1] = (short)f2bf(f0.y);
        tt[2] = (short)f2bf(f0.z); tt[3] = (short)f2bf(f0.w);
        tt[4] = (short)f2bf(f1.x); tt[5] = (short)f2bf(f1.y);
        tt[6] = (short)f2bf(f1.z); tt[7] = (short)f2bf(f1.w);
        a[kk] = tt;
      }
    } else {
      const unsigned short* A = (const unsigned short*)Ap + (size_t)row * 128 + q * 8;
#pragma unroll
      for (int kk = 0; kk < 4; kk++) a[kk] = *(const bf16x8*)(A + kk * 32);
    }
    f32x4 acc[NT];
#pragma unroll
    for (int nt = 0; nt < NT; nt++) { acc[nt][0] = 0.f; acc[nt][1] = 0.f; acc[nt][2] = 0.f; acc[nt][3] = 0.f; }
#pragma unroll
    for (int kk = 0; kk < 4; kk++) {
#pragma unroll
      for (int nt = 0; nt < NT; nt++) {
        bf16x8 bfr = *(const bf16x8*)&Ws[(nt * 16 + r) * 136 + kk * 32 + q * 8];
        acc[nt] = __builtin_amdgcn_mfma_f32_16x16x32_bf16(a[kk], bfr, acc[nt], 0, 0, 0);
      }
    }
#pragma unroll
    for (int rr = 0; rr < 4; rr++) {
      int orow = tile * 16 + q * 4 + rr;
      float rs = SCALE ? rowscale[orow] : 1.f;
#pragma unroll
      for (int nt = 0; nt < NT; nt++) {
        int ocol = nt * 16 + r;
        if (OUTF32)
          ((float*)Cp)[(size_t)orow * NCOL + ocol] = acc[nt][rr] + bias[ocol];
        else
          ((unsigned short*)Cp)[(size_t)orow * NCOL + ocol] = f2bf(acc[nt][rr] * rs);
      }
    }
  }
}

// ---------------- aggregation v6 (proven): lane-owns-2-dims, 16-deep pipeline ------
// hs rows are already h*dinv[src]. out = relu((Σ_{s∈in∪self} hs[s]) * dinv[node] + b).
__global__ __launch_bounds__(256) void agg_k(const unsigned short* __restrict__ hs,
                                             const float* __restrict__ dinv,
                                             const int* __restrict__ row_start,
                                             const int* __restrict__ csr,
                                             const float* __restrict__ bias,
                                             unsigned short* __restrict__ out, int N) {
  int lane = threadIdx.x & 63;
  int node = (blockIdx.x * 256 + threadIdx.x) >> 6;
  if (node >= N) return;
  float di = dinv[node];
  int beg = row_start[node];
  int deg = row_start[node + 1] - beg;

  const unsigned short* colp = hs + lane * 2;  // per-lane column base (4B aligned)

  f32x2 acc; acc[0] = 0.f; acc[1] = 0.f;

  for (int base = -1; base < deg; base += 64) {
    int idx = base + lane;
    int s = node;  // slot -1 (self) and invalid slots default to node
    if (idx >= 0 && idx < deg) s = csr[beg + idx];
    int cntv = deg - base; if (cntv > 64) cntv = 64;
    int j = 0;
    // ---- unmasked main: 16 edges, 16 gathers in flight ----
    for (; j + 16 <= cntv; j += 16) {
      unsigned u[16];
#pragma unroll
      for (int k = 0; k < 16; k++) {
        int sj = __builtin_amdgcn_readlane(s, j + k);
        u[k] = *(const unsigned*)(colp + (size_t)sj * 128);
      }
#pragma unroll
      for (int k = 0; k < 16; k++) {
        f32x2 p;
        p[0] = __uint_as_float(u[k] << 16);
        p[1] = __uint_as_float(u[k] & 0xffff0000u);
        acc += p;
      }
    }
    // ---- masked remainder: single 16-wide pass (wave-uniform weights) ----
    if (j < cntv) {
      unsigned u[16];
      float w[16];
#pragma unroll
      for (int k = 0; k < 16; k++) {
        int sj = __builtin_amdgcn_readlane(s, (j + k) & 63);  // wrap: any lane is valid
        u[k] = *(const unsigned*)(colp + (size_t)sj * 128);
        w[k] = (j + k < cntv) ? 1.f : 0.f;
      }
#pragma unroll
      for (int k = 0; k < 16; k++) {
        f32x2 p;
        p[0] = __uint_as_float(u[k] << 16);
        p[1] = __uint_as_float(u[k] & 0xffff0000u);
        f32x2 wv; wv[0] = w[k]; wv[1] = w[k];
        acc += p * wv;
      }
    }
  }

  f32x2 bv = *(const f32x2*)(bias + lane * 2);
  float v0 = acc[0] * di + bv[0];
  float v1 = acc[1] * di + bv[1];
  if (v0 < 0.f) v0 = 0.f;
  if (v1 < 0.f) v1 = 0.f;
  unsigned pk = ((unsigned)f2bf(v1) << 16) | (unsigned)f2bf(v0);
  *(unsigned*)(out + (size_t)node * 128 + lane * 2) = pk;
}

extern "C" void kernel_launch(void* const* d_in, const int* in_sizes, int n_in,
                              void* d_out, int out_size, void* d_ws, size_t ws_size,
                              hipStream_t stream) {
  const float* x  = (const float*)d_in[0];
  const int* ei   = (const int*)d_in[1];
  const float* W1 = (const float*)d_in[2];
  const float* b1 = (const float*)d_in[3];
  const float* W2 = (const float*)d_in[4];
  const float* b2 = (const float*)d_in[5];
  const float* fcW = (const float*)d_in[6];
  const float* fcb = (const float*)d_in[7];
  float* out = (float*)d_out;

  int N = in_sizes[0] / 128;  // 100000
  int E = in_sizes[1] / 2;    // 1600000
  int B = (N + 255) >> 8;     // 391 buckets
  const int* src = ei;
  const int* dst = ei + E;

  char* w = (char*)d_ws;
  auto alloc = [&](size_t b) { char* p = w; w += (b + 255) & ~(size_t)255; return p; };
  float* dinv      = (float*)alloc((size_t)N * 4);
  int*   row_start = (int*)alloc((size_t)(N + 1) * 4);
  int*   batom     = (int*)alloc((size_t)(B + 1) * 128);  // bcnt + bfill, stride-16 each
  unsigned* ebuf   = (unsigned*)alloc((size_t)E * 4);
  int*   csr       = (int*)alloc((size_t)E * 4);
  unsigned short* bufA = (unsigned short*)alloc((size_t)N * 128 * 2);
  unsigned short* bufB = (unsigned short*)alloc((size_t)N * 128 * 2);

  // ---- CSR build: one cooperative launch (zero + hist + bin + sort) ----
  {
    void* args[] = {(void*)&src, (void*)&dst, (void*)&batom, (void*)&ebuf,
                    (void*)&csr, (void*)&row_start, (void*)&dinv,
                    (void*)&N, (void*)&E, (void*)&B};
    hipLaunchCooperativeKernel((const void*)csr_k, dim3(B), dim3(256), args, 0, stream);
  }

  // layer 1: hs1 = (x @ W1) * dinv[row]   (fp32 in, bf16 out, row-scaled)
  gemm_k<128, true, false, true><<<782, 256, 0, stream>>>((const void*)x, W1, nullptr, dinv,
                                                          (void*)bufA, N);
  // agg1: a1 = relu(sum(hs1) * dinv + b1)  (bf16)
  agg_k<<<(N + 3) / 4, 256, 0, stream>>>(bufA, dinv, row_start, csr, b1, bufB, N);
  // layer 2: hs2 = (a1 @ W2) * dinv[row]
  gemm_k<128, false, false, true><<<782, 256, 0, stream>>>((const void*)bufB, W2, nullptr, dinv,
                                                           (void*)bufA, N);
  // agg2: a2 = relu(sum(hs2) * dinv + b2)
  agg_k<<<(N + 3) / 4, 256, 0, stream>>>(bufA, dinv, row_start, csr, b2, bufB, N);
  // fc: out = a2 @ fcW + fcb  (fp32 out)
  gemm_k<64, false, true, false><<<782, 256, 0, stream>>>((const void*)bufB, fcW, fcb, nullptr,
                                                          (void*)out, N);
}

// Round 5
// 349.314 us; speedup vs baseline: 1.3875x; 1.3875x over previous
//
#include <hip/hip_runtime.h>

typedef __attribute__((ext_vector_type(8))) short bf16x8;
typedef __attribute__((ext_vector_type(4))) float f32x4;
typedef __attribute__((ext_vector_type(2))) float f32x2;

__device__ __forceinline__ unsigned short f2bf(float x) {
  union { float f; unsigned u; } v; v.f = x;
  return (unsigned short)((v.u + 0x7fffu + ((v.u >> 16) & 1u)) >> 16);
}

// ============ node 1: fat kernel = gemm1 (x@W1 -> bf16) + partial dst-histogram ============
// Blocks [0,256): per-block partial histogram phist[i][b] of dst buckets (non-atomic write).
// Blocks [256, 256+G1): gemm1, fp32 in, bf16 out, NO row-scale (dinv folded into agg1).
// Bucket = dst>>8 (256 nodes/bucket, B=391). Edge chunking MUST match bin_k (P=256).
__global__ __launch_bounds__(256) void g1hist_k(const float* __restrict__ x,
                                                const float* __restrict__ W,
                                                unsigned short* __restrict__ C, int M,
                                                const int* __restrict__ dst,
                                                int* __restrict__ phist, int E, int B,
                                                int G1) {
  __shared__ __align__(16) unsigned short Ws[128 * 136];  // gemm: [n][k] pad 136
  int tid = threadIdx.x;

  if ((int)blockIdx.x < 256) {
    // ---- partial histogram path ----
    int i = blockIdx.x;
    int* h = (int*)Ws;  // reuse LDS
    for (int b = tid; b < B; b += 256) h[b] = 0;
    __syncthreads();
    int chunk = (E + 255) / 256;
    int e0 = i * chunk;
    int e1 = e0 + chunk; if (e1 > E) e1 = E;
    for (int e = e0 + tid; e < e1; e += 256) atomicAdd(&h[dst[e] >> 8], 1);
    __syncthreads();
    for (int b = tid; b < B; b += 256) phist[i * B + b] = h[b];
    return;
  }

  // ---- gemm1 path ----
  for (int e = tid; e < 128 * 128; e += 256) {
    int k = e / 128, n = e % 128;
    Ws[n * 136 + k] = f2bf(W[e]);
  }
  __syncthreads();

  int wave = tid >> 6, lane = tid & 63;
  int q = lane >> 4, r = lane & 15;
  int ntile = M >> 4;
  int bid = blockIdx.x - 256;
  for (int tile = bid * 4 + wave; tile < ntile; tile += G1 * 4) {
    int row = tile * 16 + r;
    bf16x8 a[4];
    const float* A = x + (size_t)row * 128 + q * 8;
#pragma unroll
    for (int kk = 0; kk < 4; kk++) {
      const float4* p = (const float4*)(A + kk * 32);
      float4 f0 = p[0], f1 = p[1];
      bf16x8 tt;
      tt[0] = (short)f2bf(f0.x); tt[1] = (short)f2bf(f0.y);
      tt[2] = (short)f2bf(f0.z); tt[3] = (short)f2bf(f0.w);
      tt[4] = (short)f2bf(f1.x); tt[5] = (short)f2bf(f1.y);
      tt[6] = (short)f2bf(f1.z); tt[7] = (short)f2bf(f1.w);
      a[kk] = tt;
    }
    f32x4 acc[8];
#pragma unroll
    for (int nt = 0; nt < 8; nt++) { acc[nt][0] = 0.f; acc[nt][1] = 0.f; acc[nt][2] = 0.f; acc[nt][3] = 0.f; }
#pragma unroll
    for (int kk = 0; kk < 4; kk++) {
#pragma unroll
      for (int nt = 0; nt < 8; nt++) {
        bf16x8 bfr = *(const bf16x8*)&Ws[(nt * 16 + r) * 136 + kk * 32 + q * 8];
        acc[nt] = __builtin_amdgcn_mfma_f32_16x16x32_bf16(a[kk], bfr, acc[nt], 0, 0, 0);
      }
    }
#pragma unroll
    for (int rr = 0; rr < 4; rr++) {
      int orow = tile * 16 + q * 4 + rr;
#pragma unroll
      for (int nt = 0; nt < 8; nt++) {
        int ocol = nt * 16 + r;
        C[(size_t)orow * 128 + ocol] = f2bf(acc[nt][rr]);
      }
    }
  }
}

// ============ node 2: bin — reservation from partial hists (no global atomics) ============
// Block j scatters edge chunk j. Cursor base: gbase[b] + sum_{i<j} phist[i][b].
// Block 0 writes gbase/btot for bsort. Record = (dst&255)<<17 | src.
__global__ __launch_bounds__(256) void bin_k(const int* __restrict__ src,
                                             const int* __restrict__ dst,
                                             const int* __restrict__ phist,
                                             int* __restrict__ gbase,
                                             int* __restrict__ btot,
                                             unsigned* __restrict__ ebuf, int E, int B) {
  __shared__ int hist[512];
  __shared__ int pre[512];
  __shared__ int tot[512];
  __shared__ int sd[256];
  int t = threadIdx.x;
  int j = blockIdx.x;  // 0..255

  for (int b = t; b < 512; b += 256) { pre[b] = 0; tot[b] = 0; }
  __syncthreads();
  for (int b = t; b < B; b += 256) {
    int s = 0, p = 0;
    for (int i = 0; i < 256; i++) {
      if (i == j) p = s;
      s += phist[i * B + b];
    }
    pre[b] = p;
    tot[b] = s;
  }
  __syncthreads();
  // exclusive scan of tot -> bucket global base
  int i0 = 2 * t, i1 = 2 * t + 1;
  int v0 = tot[i0], v1 = tot[i1];
  int ts = v0 + v1;
  sd[t] = ts; __syncthreads();
  for (int off = 1; off < 256; off <<= 1) {
    int xx = (t >= off) ? sd[t - off] : 0;
    __syncthreads();
    sd[t] += xx;
    __syncthreads();
  }
  int excl = sd[t] - ts;
  hist[i0] = excl + pre[i0];
  hist[i1] = excl + v0 + pre[i1];
  if (j == 0) {
    if (i0 < B) { gbase[i0] = excl;      btot[i0] = v0; }
    if (i1 < B) { gbase[i1] = excl + v0; btot[i1] = v1; }
  }
  __syncthreads();

  int chunk = (E + 255) / 256;
  int e0 = j * chunk;
  int e1 = e0 + chunk; if (e1 > E) e1 = E;
  for (int e = e0 + t; e < e1; e += 256) {
    int d = dst[e];
    int b = d >> 8;
    int pos = atomicAdd(&hist[b], 1);  // LDS atomic
    ebuf[pos] = ((unsigned)(d & 255) << 17) | (unsigned)src[e];
  }
}

// ============ node 3: per-bucket LDS counting sort -> CSR + row_start + dinv ============
__global__ __launch_bounds__(256) void bsort_k(const unsigned* __restrict__ ebuf,
                                               const int* __restrict__ gbase,
                                               const int* __restrict__ btot,
                                               int* __restrict__ csr,
                                               int* __restrict__ row_start,
                                               float* __restrict__ dinv, int N, int B, int E) {
  __shared__ int cnt[256];
  __shared__ int sd[256];
  __shared__ int ofs[256];
  __shared__ int sorted[8192];  // bucket mean 4092, sigma ~64
  int b = blockIdx.x, t = threadIdx.x;
  int bs = gbase[b];
  int m = btot[b];
  if (b == 0 && t == 0) row_start[N] = E;
  if (m > 8192) m = 8192;

  cnt[t] = 0;
  __syncthreads();
  for (int i = t; i < m; i += 256) atomicAdd(&cnt[ebuf[bs + i] >> 17], 1);
  __syncthreads();
  int deg = cnt[t];
  sd[t] = deg; __syncthreads();
  for (int off = 1; off < 256; off <<= 1) {
    int x = (t >= off) ? sd[t - off] : 0;
    __syncthreads();
    sd[t] += x;
    __syncthreads();
  }
  int nexcl = sd[t] - deg;
  ofs[t] = nexcl;
  int node = (b << 8) + t;
  if (node < N) {
    row_start[node] = bs + nexcl;
    dinv[node] = rsqrtf((float)(deg + 1));
  }
  __syncthreads();
  for (int i = t; i < m; i += 256) {
    unsigned r = ebuf[bs + i];
    int d = r >> 17;
    int p = atomicAdd(&ofs[d], 1);
    if (p < 8192) sorted[p] = (int)(r & 0x1FFFFu);
  }
  __syncthreads();
  for (int i = t; i < m; i += 256) csr[bs + i] = sorted[i];
}

// ---------------- GEMM: [M,128] @ [128,NCOL] via 16x16x32 bf16 MFMA ----------------
// SCALE: multiply each output row by rowscale[row] before bf16 pack (dinv folding).
template <int NCOL, bool OUTF32, bool SCALE>
__global__ __launch_bounds__(256) void gemm_k(const void* __restrict__ Ap,
                                              const float* __restrict__ W,
                                              const float* __restrict__ bias,
                                              const float* __restrict__ rowscale,
                                              void* __restrict__ Cp, int M) {
  __shared__ __align__(16) unsigned short Ws[NCOL * 136];  // [n][k], pad k to 136
  int tid = threadIdx.x;
  for (int e = tid; e < 128 * NCOL; e += 256) {
    int k = e / NCOL, n = e % NCOL;
    Ws[n * 136 + k] = f2bf(W[e]);
  }
  __syncthreads();

  int wave = tid >> 6, lane = tid & 63;
  int q = lane >> 4, r = lane & 15;
  const int NT = NCOL / 16;
  int ntile = M >> 4;
  for (int tile = blockIdx.x * 4 + wave; tile < ntile; tile += gridDim.x * 4) {
    int row = tile * 16 + r;
    bf16x8 a[4];
    const unsigned short* A = (const unsigned short*)Ap + (size_t)row * 128 + q * 8;
#pragma unroll
    for (int kk = 0; kk < 4; kk++) a[kk] = *(const bf16x8*)(A + kk * 32);
    f32x4 acc[NT];
#pragma unroll
    for (int nt = 0; nt < NT; nt++) { acc[nt][0] = 0.f; acc[nt][1] = 0.f; acc[nt][2] = 0.f; acc[nt][3] = 0.f; }
#pragma unroll
    for (int kk = 0; kk < 4; kk++) {
#pragma unroll
      for (int nt = 0; nt < NT; nt++) {
        bf16x8 bfr = *(const bf16x8*)&Ws[(nt * 16 + r) * 136 + kk * 32 + q * 8];
        acc[nt] = __builtin_amdgcn_mfma_f32_16x16x32_bf16(a[kk], bfr, acc[nt], 0, 0, 0);
      }
    }
#pragma unroll
    for (int rr = 0; rr < 4; rr++) {
      int orow = tile * 16 + q * 4 + rr;
      float rs = SCALE ? rowscale[orow] : 1.f;
#pragma unroll
      for (int nt = 0; nt < NT; nt++) {
        int ocol = nt * 16 + r;
        if (OUTF32)
          ((float*)Cp)[(size_t)orow * NCOL + ocol] = acc[nt][rr] + bias[ocol];
        else
          ((unsigned short*)Cp)[(size_t)orow * NCOL + ocol] = f2bf(acc[nt][rr] * rs);
      }
    }
  }
}

// ---------------- aggregation v6 (proven): lane-owns-2-dims, 16-deep pipeline ------
// ESCALE=false: hs rows pre-scaled -> out = relu((Σ hs[s]) * dinv[node] + b).
// ESCALE=true:  hs rows raw      -> out = relu((Σ dinv[s]*hs[s]) * dinv[node] + b).
// sj is wave-uniform (readlane) so dinv[sj] is a scalar load (L2-hot 400KB).
template <bool ESCALE>
__global__ __launch_bounds__(256) void agg_k(const unsigned short* __restrict__ hs,
                                             const float* __restrict__ dinv,
                                             const int* __restrict__ row_start,
                                             const int* __restrict__ csr,
                                             const float* __restrict__ bias,
                                             unsigned short* __restrict__ out, int N) {
  int lane = threadIdx.x & 63;
  int node = (blockIdx.x * 256 + threadIdx.x) >> 6;
  if (node >= N) return;
  float di = dinv[node];
  int beg = row_start[node];
  int deg = row_start[node + 1] - beg;

  const unsigned short* colp = hs + lane * 2;  // per-lane column base (4B aligned)

  f32x2 acc; acc[0] = 0.f; acc[1] = 0.f;

  for (int base = -1; base < deg; base += 64) {
    int idx = base + lane;
    int s = node;  // slot -1 (self) and invalid slots default to node
    if (idx >= 0 && idx < deg) s = csr[beg + idx];
    int cntv = deg - base; if (cntv > 64) cntv = 64;
    int j = 0;
    // ---- unmasked main: 16 edges, 16 gathers in flight ----
    for (; j + 16 <= cntv; j += 16) {
      unsigned u[16];
      float dv[16];
#pragma unroll
      for (int k = 0; k < 16; k++) {
        int sj = __builtin_amdgcn_readlane(s, j + k);
        u[k] = *(const unsigned*)(colp + (size_t)sj * 128);
        if (ESCALE) dv[k] = dinv[sj];
      }
#pragma unroll
      for (int k = 0; k < 16; k++) {
        f32x2 p;
        p[0] = __uint_as_float(u[k] << 16);
        p[1] = __uint_as_float(u[k] & 0xffff0000u);
        if (ESCALE) { acc[0] += p[0] * dv[k]; acc[1] += p[1] * dv[k]; }
        else        { acc += p; }
      }
    }
    // ---- masked remainder: single 16-wide pass (wave-uniform weights) ----
    if (j < cntv) {
      unsigned u[16];
      float w[16];
#pragma unroll
      for (int k = 0; k < 16; k++) {
        int sj = __builtin_amdgcn_readlane(s, (j + k) & 63);  // wrap: any lane is valid
        u[k] = *(const unsigned*)(colp + (size_t)sj * 128);
        w[k] = (j + k < cntv) ? 1.f : 0.f;
        if (ESCALE) w[k] *= dinv[sj];
      }
#pragma unroll
      for (int k = 0; k < 16; k++) {
        f32x2 p;
        p[0] = __uint_as_float(u[k] << 16);
        p[1] = __uint_as_float(u[k] & 0xffff0000u);
        acc[0] += p[0] * w[k];
        acc[1] += p[1] * w[k];
      }
    }
  }

  f32x2 bv = *(const f32x2*)(bias + lane * 2);
  float v0 = acc[0] * di + bv[0];
  float v1 = acc[1] * di + bv[1];
  if (v0 < 0.f) v0 = 0.f;
  if (v1 < 0.f) v1 = 0.f;
  unsigned pk = ((unsigned)f2bf(v1) << 16) | (unsigned)f2bf(v0);
  *(unsigned*)(out + (size_t)node * 128 + lane * 2) = pk;
}

extern "C" void kernel_launch(void* const* d_in, const int* in_sizes, int n_in,
                              void* d_out, int out_size, void* d_ws, size_t ws_size,
                              hipStream_t stream) {
  const float* x  = (const float*)d_in[0];
  const int* ei   = (const int*)d_in[1];
  const float* W1 = (const float*)d_in[2];
  const float* b1 = (const float*)d_in[3];
  const float* W2 = (const float*)d_in[4];
  const float* b2 = (const float*)d_in[5];
  const float* fcW = (const float*)d_in[6];
  const float* fcb = (const float*)d_in[7];
  float* out = (float*)d_out;

  int N = in_sizes[0] / 128;  // 100000
  int E = in_sizes[1] / 2;    // 1600000
  int B = (N + 255) >> 8;     // 391 buckets
  const int* src = ei;
  const int* dst = ei + E;

  char* w = (char*)d_ws;
  auto alloc = [&](size_t b) { char* p = w; w += (b + 255) & ~(size_t)255; return p; };
  float* dinv      = (float*)alloc((size_t)N * 4);
  int*   row_start = (int*)alloc((size_t)(N + 1) * 4);
  int*   phist     = (int*)alloc((size_t)256 * B * 4);
  int*   gbase     = (int*)alloc((size_t)B * 4);
  int*   btot      = (int*)alloc((size_t)B * 4);
  unsigned* ebuf   = (unsigned*)alloc((size_t)E * 4);
  int*   csr       = (int*)alloc((size_t)E * 4);
  unsigned short* bufA = (unsigned short*)alloc((size_t)N * 128 * 2);
  unsigned short* bufB = (unsigned short*)alloc((size_t)N * 128 * 2);

  const int G1 = 782;

  // node 1: gemm1 (no scale) + partial dst histogram (overlapped, independent)
  g1hist_k<<<256 + G1, 256, 0, stream>>>(x, W1, bufA, N, dst, phist, E, B, G1);
  // node 2: bin (reservation from partials; block 0 emits gbase/btot)
  bin_k<<<256, 256, 0, stream>>>(src, dst, phist, gbase, btot, ebuf, E, B);
  // node 3: per-bucket sort -> csr, row_start, dinv
  bsort_k<<<B, 256, 0, stream>>>(ebuf, gbase, btot, csr, row_start, dinv, N, B, E);
  // node 4: agg1 = relu((Σ dinv[s]*hs1[s]) * dinv + b1)
  agg_k<true><<<(N + 3) / 4, 256, 0, stream>>>(bufA, dinv, row_start, csr, b1, bufB, N);
  // node 5: hs2 = (a1 @ W2) * dinv[row]
  gemm_k<128, false, true><<<782, 256, 0, stream>>>((const void*)bufB, W2, nullptr, dinv,
                                                    (void*)bufA, N);
  // node 6: agg2 = relu((Σ hs2[s]) * dinv + b2)
  agg_k<false><<<(N + 3) / 4, 256, 0, stream>>>(bufA, dinv, row_start, csr, b2, bufB, N);
  // node 7: out = a2 @ fcW + fcb
  gemm_k<64, true, false><<<782, 256, 0, stream>>>((const void*)bufB, fcW, fcb, nullptr,
                                                   (void*)out, N);
}

// Round 7
// 333.278 us; speedup vs baseline: 1.4542x; 1.0481x over previous
//
#include <hip/hip_runtime.h>

typedef __attribute__((ext_vector_type(8))) short bf16x8;
typedef __attribute__((ext_vector_type(4))) float f32x4;
typedef __attribute__((ext_vector_type(2))) float f32x2;

__device__ __forceinline__ unsigned short f2bf(float x) {
  union { float f; unsigned u; } v; v.f = x;
  return (unsigned short)((v.u + 0x7fffu + ((v.u >> 16) & 1u)) >> 16);
}

// ================= CSR build: two-level counting sort by dst =================
// Bucket = dst >> 8 (256 nodes/bucket). Record = (dst&255)<<17 | src (25 bits).
// bcnt/bfill: one counter per 64B line (stride-16 ints).

__global__ __launch_bounds__(256) void bhist_k(const int* __restrict__ dst,
                                               int* __restrict__ bcnt, int E, int B) {
  __shared__ int h[512];
  for (int i = threadIdx.x; i < B; i += 256) h[i] = 0;
  __syncthreads();
  for (int e = blockIdx.x * 256 + threadIdx.x; e < E; e += gridDim.x * 256)
    atomicAdd(&h[dst[e] >> 8], 1);
  __syncthreads();
  for (int i = threadIdx.x; i < B; i += 256)
    if (h[i]) atomicAdd(&bcnt[i * 16], h[i]);
}

// -- binning: local bucket scan + per-block LDS hist + one reservation per (block,bucket) --
__global__ __launch_bounds__(256) void bin_k(const int* __restrict__ src,
                                             const int* __restrict__ dst,
                                             const int* __restrict__ bcnt,
                                             int* __restrict__ bfill,
                                             unsigned* __restrict__ ebuf, int E, int B) {
  __shared__ int hist[512];
  __shared__ int base[512];
  __shared__ int sd[256];
  int t = threadIdx.x;
  int i0 = 2 * t, i1 = 2 * t + 1;
  int v0 = (i0 < B) ? bcnt[i0 * 16] : 0;
  int v1 = (i1 < B) ? bcnt[i1 * 16] : 0;
  int ts = v0 + v1;
  sd[t] = ts; __syncthreads();
  for (int off = 1; off < 256; off <<= 1) {
    int x = (t >= off) ? sd[t - off] : 0;
    __syncthreads();
    sd[t] += x;
    __syncthreads();
  }
  int excl = sd[t] - ts;
  base[i0] = excl;
  base[i1] = excl + v0;
  __syncthreads();

  int chunk = (E + gridDim.x - 1) / gridDim.x;
  int e0 = blockIdx.x * chunk;
  int e1 = e0 + chunk; if (e1 > E) e1 = E;
  for (int i = t; i < B; i += 256) hist[i] = 0;
  __syncthreads();
  for (int e = e0 + t; e < e1; e += 256) atomicAdd(&hist[dst[e] >> 8], 1);
  __syncthreads();
  for (int i = t; i < B; i += 256) {
    int c = hist[i];
    hist[i] = base[i] + (c ? atomicAdd(&bfill[i * 16], c) : 0);
  }
  __syncthreads();
  for (int e = e0 + t; e < e1; e += 256) {
    int d = dst[e];
    int b = d >> 8;
    int pos = atomicAdd(&hist[b], 1);  // LDS atomic
    ebuf[pos] = ((unsigned)(d & 255) << 17) | (unsigned)src[e];
  }
}

// -- per-bucket LDS counting sort -> coalesced CSR (src only) + row_start + dinv --
__global__ __launch_bounds__(256) void bsort_k(const unsigned* __restrict__ ebuf,
                                               const int* __restrict__ bcnt,
                                               int* __restrict__ csr,
                                               int* __restrict__ row_start,
                                               float* __restrict__ dinv, int N, int B, int E) {
  __shared__ int cnt[256];
  __shared__ int sd[256];
  __shared__ int ofs[256];
  __shared__ int sorted[8192];  // mean 4096, sigma ~64
  __shared__ int s_bs, s_m;
  int b = blockIdx.x, t = threadIdx.x;
  int i0 = 2 * t, i1 = 2 * t + 1;
  int v0 = (i0 < B) ? bcnt[i0 * 16] : 0;
  int v1 = (i1 < B) ? bcnt[i1 * 16] : 0;
  int ts = v0 + v1;
  sd[t] = ts; __syncthreads();
  for (int off = 1; off < 256; off <<= 1) {
    int x = (t >= off) ? sd[t - off] : 0;
    __syncthreads();
    sd[t] += x;
    __syncthreads();
  }
  int excl = sd[t] - ts;
  if (i0 == b) { s_bs = excl; s_m = v0; }
  if (i1 == b) { s_bs = excl + v0; s_m = v1; }
  if (b == 0 && t == 0) row_start[N] = E;
  __syncthreads();
  int bs = s_bs, m = s_m;
  if (m > 8192) m = 8192;

  cnt[t] = 0;
  __syncthreads();
  for (int i = t; i < m; i += 256) atomicAdd(&cnt[ebuf[bs + i] >> 17], 1);
  __syncthreads();
  int deg = cnt[t];
  sd[t] = deg; __syncthreads();
  for (int off = 1; off < 256; off <<= 1) {
    int x = (t >= off) ? sd[t - off] : 0;
    __syncthreads();
    sd[t] += x;
    __syncthreads();
  }
  int nexcl = sd[t] - deg;
  ofs[t] = nexcl;
  int node = (b << 8) + t;
  if (node < N) {
    row_start[node] = bs + nexcl;
    dinv[node] = rsqrtf((float)(deg + 1));
  }
  __syncthreads();
  for (int i = t; i < m; i += 256) {
    unsigned r = ebuf[bs + i];
    int d = r >> 17;
    int p = atomicAdd(&ofs[d], 1);
    if (p < 8192) sorted[p] = (int)(r & 0x1FFFFu);
  }
  __syncthreads();
  for (int i = t; i < m; i += 256) csr[bs + i] = sorted[i];
}

// ---------------- GEMM: [M,128] @ [128,NCOL] via 16x16x32 bf16 MFMA ----------------
// SCALE: multiply each output row by rowscale[row] before bf16 pack (dinv folding).
template <int NCOL, bool INF32, bool OUTF32, bool SCALE>
__global__ __launch_bounds__(256) void gemm_k(const void* __restrict__ Ap,
                                              const float* __restrict__ W,
                                              const float* __restrict__ bias,
                                              const float* __restrict__ rowscale,
                                              void* __restrict__ Cp, int M) {
  __shared__ __align__(16) unsigned short Ws[NCOL * 136];  // [n][k], pad k to 136
  int tid = threadIdx.x;
  for (int e = tid; e < 128 * NCOL; e += 256) {
    int k = e / NCOL, n = e % NCOL;
    Ws[n * 136 + k] = f2bf(W[e]);
  }
  __syncthreads();

  int wave = tid >> 6, lane = tid & 63;
  int q = lane >> 4, r = lane & 15;
  const int NT = NCOL / 16;
  int ntile = M >> 4;
  for (int tile = blockIdx.x * 4 + wave; tile < ntile; tile += gridDim.x * 4) {
    int row = tile * 16 + r;
    bf16x8 a[4];
    if (INF32) {
      const float* A = (const float*)Ap + (size_t)row * 128 + q * 8;
#pragma unroll
      for (int kk = 0; kk < 4; kk++) {
        const float4* p = (const float4*)(A + kk * 32);
        float4 f0 = p[0], f1 = p[1];
        bf16x8 tt;
        tt[0] = (short)f2bf(f0.x); tt[1] = (short)f2bf(f0.y);
        tt[2] = (short)f2bf(f0.z); tt[3] = (short)f2bf(f0.w);
        tt[4] = (short)f2bf(f1.x); tt[5] = (short)f2bf(f1.y);
        tt[6] = (short)f2bf(f1.z); tt[7] = (short)f2bf(f1.w);
        a[kk] = tt;
      }
    } else {
      const unsigned short* A = (const unsigned short*)Ap + (size_t)row * 128 + q * 8;
#pragma unroll
      for (int kk = 0; kk < 4; kk++) a[kk] = *(const bf16x8*)(A + kk * 32);
    }
    f32x4 acc[NT];
#pragma unroll
    for (int nt = 0; nt < NT; nt++) { acc[nt][0] = 0.f; acc[nt][1] = 0.f; acc[nt][2] = 0.f; acc[nt][3] = 0.f; }
#pragma unroll
    for (int kk = 0; kk < 4; kk++) {
#pragma unroll
      for (int nt = 0; nt < NT; nt++) {
        bf16x8 bfr = *(const bf16x8*)&Ws[(nt * 16 + r) * 136 + kk * 32 + q * 8];
        acc[nt] = __builtin_amdgcn_mfma_f32_16x16x32_bf16(a[kk], bfr, acc[nt], 0, 0, 0);
      }
    }
#pragma unroll
    for (int rr = 0; rr < 4; rr++) {
      int orow = tile * 16 + q * 4 + rr;
      float rs = SCALE ? rowscale[orow] : 1.f;
#pragma unroll
      for (int nt = 0; nt < NT; nt++) {
        int ocol = nt * 16 + r;
        if (OUTF32)
          ((float*)Cp)[(size_t)orow * NCOL + ocol] = acc[nt][rr] + bias[ocol];
        else
          ((unsigned short*)Cp)[(size_t)orow * NCOL + ocol] = f2bf(acc[nt][rr] * rs);
      }
    }
  }
}

// ---------------- aggregation v8: half-dim split (working-set halving) -------------
// hs rows pre-scaled (h*dinv[src]); out = relu((Σ hs[s]) * dinv[node] + b).
// Blocks [0,G): dims 0-63; blocks [G,2G): dims 64-127 -> per-pass gather working set
// is 12.8MB (vs 25.6), doubling per-XCD L2 residency. Same math per dim.
// Wave = 2 nodes x 32 lanes; lane owns 2 dims of its half (4B/lane, 128B/group = 2
// full lines per edge). 16 gathers in flight; group-relative __shfl broadcast.
__global__ __launch_bounds__(256) void agg_k(const unsigned short* __restrict__ hs,
                                             const float* __restrict__ dinv,
                                             const int* __restrict__ row_start,
                                             const int* __restrict__ csr,
                                             const float* __restrict__ bias,
                                             unsigned short* __restrict__ out, int N, int G) {
  int lane = threadIdx.x & 63;
  int wid = threadIdx.x >> 6;
  int half = (blockIdx.x >= G) ? 1 : 0;
  int blk = blockIdx.x - half * G;
  int l = lane & 31;  // lane within node-group
  int node = blk * 8 + wid * 2 + (lane >> 5);
  if (node >= N) return;
  float di = dinv[node];
  int beg = row_start[node];
  int deg = row_start[node + 1] - beg;

  const unsigned short* colp = hs + half * 64 + l * 2;  // per-lane column base

  f32x2 acc; acc[0] = 0.f; acc[1] = 0.f;

  for (int base = -1; base < deg; base += 32) {
    int idx = base + l;
    int s = node;  // slot -1 (self, l==0 first window) and invalid slots -> node
    if (idx >= 0 && idx < deg) s = csr[beg + idx];
    int cntv = deg - base; if (cntv > 32) cntv = 32;
    int j = 0;
    // ---- unmasked main: 16 edges, 16 gathers in flight ----
    for (; j + 16 <= cntv; j += 16) {
      unsigned u[16];
#pragma unroll
      for (int k = 0; k < 16; k++) {
        int sj = __shfl(s, j + k, 32);  // group-relative broadcast
        u[k] = *(const unsigned*)(colp + (size_t)sj * 128);
      }
#pragma unroll
      for (int k = 0; k < 16; k++) {
        f32x2 p;
        p[0] = __uint_as_float(u[k] << 16);
        p[1] = __uint_as_float(u[k] & 0xffff0000u);
        acc += p;
      }
    }
    // ---- masked remainder: single 16-wide pass (group-uniform weights) ----
    if (j < cntv) {
      unsigned u[16];
      float w[16];
#pragma unroll
      for (int k = 0; k < 16; k++) {
        int sj = __shfl(s, (j + k) & 31, 32);  // wrap: any slot is a valid row
        u[k] = *(const unsigned*)(colp + (size_t)sj * 128);
        w[k] = (j + k < cntv) ? 1.f : 0.f;
      }
#pragma unroll
      for (int k = 0; k < 16; k++) {
        f32x2 p;
        p[0] = __uint_as_float(u[k] << 16);
        p[1] = __uint_as_float(u[k] & 0xffff0000u);
        acc[0] += p[0] * w[k];
        acc[1] += p[1] * w[k];
      }
    }
  }

  f32x2 bv = *(const f32x2*)(bias + half * 64 + l * 2);
  float v0 = acc[0] * di + bv[0];
  float v1 = acc[1] * di + bv[1];
  if (v0 < 0.f) v0 = 0.f;
  if (v1 < 0.f) v1 = 0.f;
  unsigned pk = ((unsigned)f2bf(v1) << 16) | (unsigned)f2bf(v0);
  *(unsigned*)(out + (size_t)node * 128 + half * 64 + l * 2) = pk;
}

extern "C" void kernel_launch(void* const* d_in, const int* in_sizes, int n_in,
                              void* d_out, int out_size, void* d_ws, size_t ws_size,
                              hipStream_t stream) {
  const float* x  = (const float*)d_in[0];
  const int* ei   = (const int*)d_in[1];
  const float* W1 = (const float*)d_in[2];
  const float* b1 = (const float*)d_in[3];
  const float* W2 = (const float*)d_in[4];
  const float* b2 = (const float*)d_in[5];
  const float* fcW = (const float*)d_in[6];
  const float* fcb = (const float*)d_in[7];
  float* out = (float*)d_out;

  int N = in_sizes[0] / 128;  // 100000
  int E = in_sizes[1] / 2;    // 1600000
  int B = (N + 255) >> 8;     // 391 buckets
  const int* src = ei;
  const int* dst = ei + E;

  char* w = (char*)d_ws;
  auto alloc = [&](size_t b) { char* p = w; w += (b + 255) & ~(size_t)255; return p; };
  float* dinv      = (float*)alloc((size_t)N * 4);
  int*   row_start = (int*)alloc((size_t)(N + 1) * 4);
  int*   batom     = (int*)alloc((size_t)(B + 1) * 128);  // bcnt + bfill, stride-16 each
  int*   bcnt      = batom;
  int*   bfill     = batom + (size_t)(B + 1) * 16;
  unsigned* ebuf   = (unsigned*)alloc((size_t)E * 4);
  int*   csr       = (int*)alloc((size_t)E * 4);
  unsigned short* bufA = (unsigned short*)alloc((size_t)N * 128 * 2);
  unsigned short* bufB = (unsigned short*)alloc((size_t)N * 128 * 2);

  hipMemsetAsync(batom, 0, (size_t)(B + 1) * 128, stream);

  bhist_k<<<256, 256, 0, stream>>>(dst, bcnt, E, B);
  bin_k<<<256, 256, 0, stream>>>(src, dst, bcnt, bfill, ebuf, E, B);
  bsort_k<<<B, 256, 0, stream>>>(ebuf, bcnt, csr, row_start, dinv, N, B, E);

  int G = (N + 7) / 8;  // blocks per half-dim pass

  // layer 1: hs1 = (x @ W1) * dinv[row]   (fp32 in, bf16 out, row-scaled)
  gemm_k<128, true, false, true><<<782, 256, 0, stream>>>((const void*)x, W1, nullptr, dinv,
                                                          (void*)bufA, N);
  // agg1: a1 = relu(sum(hs1) * dinv + b1)  (bf16, half-dim split)
  agg_k<<<2 * G, 256, 0, stream>>>(bufA, dinv, row_start, csr, b1, bufB, N, G);
  // layer 2: hs2 = (a1 @ W2) * dinv[row]
  gemm_k<128, false, false, true><<<782, 256, 0, stream>>>((const void*)bufB, W2, nullptr, dinv,
                                                           (void*)bufA, N);
  // agg2: a2 = relu(sum(hs2) * dinv + b2)
  agg_k<<<2 * G, 256, 0, stream>>>(bufA, dinv, row_start, csr, b2, bufB, N, G);
  // fc: out = a2 @ fcW + fcb  (fp32 out)
  gemm_k<64, false, true, false><<<782, 256, 0, stream>>>((const void*)bufB, fcW, fcb, nullptr,
                                                          (void*)out, N);
}